// Round 3
// baseline (189.327 us; speedup 1.0000x reference)
//
#include <hip/hip_runtime.h>
#include <stdint.h>

#define BM 128
#define BN 128
#define KD 256      // K dimension (D) — kernel assumes 256
#define NTJ 8       // B-tiles streamed per block

typedef __attribute__((ext_vector_type(4))) float f32x4;
typedef __attribute__((ext_vector_type(8))) short bf16x8;

__device__ __forceinline__ unsigned short f2bf(float f) {
  unsigned int u = __float_as_uint(f);
  u += 0x7FFFu + ((u >> 16) & 1u);   // round-to-nearest-even
  return (unsigned short)(u >> 16);
}

// Kernel 1: per-row normalize (fp32), cast to bf16; diag[i] = cos(a_i,b_i).
// Also zeroes the output accumulator (d_out poisoned by harness).
__global__ __launch_bounds__(256) void norm_kernel(
    const float* __restrict__ a, const float* __restrict__ b,
    unsigned short* __restrict__ an, unsigned short* __restrict__ bn,
    float* __restrict__ diag, float* __restrict__ out, int D) {
  if (blockIdx.x == 0 && threadIdx.x == 0) out[0] = 0.f;
  const int row = blockIdx.x * 4 + (threadIdx.x >> 6);
  const int l = threadIdx.x & 63;
  const float4* ar = (const float4*)(a + (size_t)row * D);
  const float4* br = (const float4*)(b + (size_t)row * D);
  const int nd4 = D >> 2;
  float ssa = 0.f, ssb = 0.f, dot = 0.f;
  for (int c = l; c < nd4; c += 64) {
    float4 av = ar[c], bv = br[c];
    ssa += av.x*av.x + av.y*av.y + av.z*av.z + av.w*av.w;
    ssb += bv.x*bv.x + bv.y*bv.y + bv.z*bv.z + bv.w*bv.w;
    dot += av.x*bv.x + av.y*bv.y + av.z*bv.z + av.w*bv.w;
  }
  for (int off = 1; off < 64; off <<= 1) {
    ssa += __shfl_xor(ssa, off, 64);
    ssb += __shfl_xor(ssb, off, 64);
    dot += __shfl_xor(dot, off, 64);
  }
  const float inva = 1.0f / sqrtf(ssa);
  const float invb = 1.0f / sqrtf(ssb);
  if (l == 0) diag[row] = dot * inva * invb;
  ushort4* anr = (ushort4*)(an + (size_t)row * D);
  ushort4* bnr = (ushort4*)(bn + (size_t)row * D);
  for (int c = l; c < nd4; c += 64) {
    float4 av = ar[c], bv = br[c];
    ushort4 ap, bp;
    ap.x = f2bf(av.x * inva); ap.y = f2bf(av.y * inva);
    ap.z = f2bf(av.z * inva); ap.w = f2bf(av.w * inva);
    bp.x = f2bf(bv.x * invb); bp.y = f2bf(bv.y * invb);
    bp.z = f2bf(bv.z * invb); bp.w = f2bf(bv.w * invb);
    anr[c] = ap; bnr[c] = bp;
  }
}

// Kernel 2: register-resident-A GEMM. Block (ti, jg): A-tile fragments for
// full K=256 loaded ONCE global->VGPR (128 VGPRs); then stream NTJ B-tiles
// through one 64 KB LDS buffer (XOR-swizzled: 16B chunk at LDS pos p of row r
// holds global chunk p ^ (r&7), applied on the global source address since
// global_load_lds's LDS side must be lane-contiguous). Per tile: full-K
// MFMA (128/wave) + label-masked max epilogue. Row-max rides in registers
// across the tj loop; col-max written per tile.
__global__ __launch_bounds__(256, 2) void gemm_max_kernel(
    const unsigned short* __restrict__ an, const unsigned short* __restrict__ bn,
    const int* __restrict__ labels,
    float* __restrict__ row_part, float* __restrict__ col_part,
    int B, int ngroups) {
  __shared__ __align__(16) unsigned short sB[BN * KD];   // 64 KB
  __shared__ float lds_row[2][BM];
  __shared__ float lds_col[2][BN];

  const int tid  = threadIdx.x;
  const int lane = tid & 63;
  const int w    = tid >> 6;
  const int wm   = w >> 1, wn = w & 1;
  const int ti   = blockIdx.x / ngroups;
  const int jg   = blockIdx.x % ngroups;

  const int fr = lane & 15;     // fragment m/n index
  const int hi = lane >> 4;     // k-subchunk quad

  // A fragments direct from global: lane holds A[m=fr][k = kc*32 + hi*8 + j]
  bf16x8 afrag[4][8];
  #pragma unroll
  for (int mt = 0; mt < 4; ++mt) {
    const unsigned short* ga =
        an + (size_t)(ti * BM + wm * 64 + mt * 16 + fr) * KD + hi * 8;
    #pragma unroll
    for (int kc = 0; kc < 8; ++kc)
      afrag[mt][kc] = *(const bf16x8*)(ga + kc * 32);
  }

  // Row labels (loop-invariant): C/D row = hi*4 + r within the mt subtile.
  int li[4][4];
  #pragma unroll
  for (int mt = 0; mt < 4; ++mt)
    #pragma unroll
    for (int r = 0; r < 4; ++r)
      li[mt][r] = labels[ti * BM + wm * 64 + mt * 16 + hi * 4 + r];

  float rmax[4][4];
  #pragma unroll
  for (int mt = 0; mt < 4; ++mt)
    #pragma unroll
    for (int r = 0; r < 4; ++r) rmax[mt][r] = -1e9f;

  const int srow2 = lane >> 5;        // row-within-pair for staging
  const int spos  = lane & 31;        // LDS 16B-chunk position within row
  const f32x4 fz = {0.f, 0.f, 0.f, 0.f};

  for (int t = 0; t < NTJ; ++t) {
    const int tj = jg * NTJ + t;

    // Stage B tile (128 x 256 bf16 = 64 KB), swizzled on the global side.
    {
      const unsigned short* gB = bn + (size_t)(tj * BN) * KD;
      #pragma unroll
      for (int c = 0; c < 16; ++c) {
        const int rr = w * 32 + c * 2 + srow2;
        const unsigned short* src = gB + (size_t)rr * KD + ((spos ^ (rr & 7)) * 8);
        unsigned short* dst = sB + (w * 32 + c * 2) * KD + lane * 8;
        __builtin_amdgcn_global_load_lds(
            (const __attribute__((address_space(1))) void*)src,
            (__attribute__((address_space(3))) void*)dst, 16, 0, 0);
      }
    }
    __syncthreads();

    // Full-K compute: 8 k-slices x 16 MFMA.
    f32x4 acc[4][4];
    #pragma unroll
    for (int kc = 0; kc < 8; ++kc) {
      bf16x8 bfrag[4];
      #pragma unroll
      for (int nt = 0; nt < 4; ++nt) {
        const int R = wn * 64 + nt * 16 + fr;
        const int q = kc * 4 + hi;
        bfrag[nt] = *(const bf16x8*)(sB + R * KD + ((q ^ (fr & 7)) * 8));
      }
      #pragma unroll
      for (int mt = 0; mt < 4; ++mt)
        #pragma unroll
        for (int nt = 0; nt < 4; ++nt)
          acc[mt][nt] = __builtin_amdgcn_mfma_f32_16x16x32_bf16(
              afrag[mt][kc], bfrag[nt], (kc == 0) ? fz : acc[mt][nt], 0, 0, 0);
    }

    // Epilogue: label-masked max (threshold test lives in finalize).
    int labc[4];
    #pragma unroll
    for (int nt = 0; nt < 4; ++nt)
      labc[nt] = labels[tj * BN + wn * 64 + nt * 16 + fr];

    float cmax[4] = {-1e9f, -1e9f, -1e9f, -1e9f};
    #pragma unroll
    for (int mt = 0; mt < 4; ++mt)
      #pragma unroll
      for (int r = 0; r < 4; ++r) {
        const int l0 = li[mt][r];
        #pragma unroll
        for (int nt = 0; nt < 4; ++nt) {
          const float vm = (l0 != labc[nt]) ? acc[mt][nt][r] : -1e9f;
          rmax[mt][r] = fmaxf(rmax[mt][r], vm);
          cmax[nt]    = fmaxf(cmax[nt], vm);
        }
      }
    #pragma unroll
    for (int nt = 0; nt < 4; ++nt) {
      float c = cmax[nt];
      c = fmaxf(c, __shfl_xor(c, 16, 64));
      c = fmaxf(c, __shfl_xor(c, 32, 64));
      if (hi == 0) lds_col[wm][wn * 64 + nt * 16 + fr] = c;
    }
    __syncthreads();   // compute + lds_col done; sB free for next stage
    if (tid < BN)
      col_part[(size_t)ti * B + tj * BN + tid] =
          fmaxf(lds_col[0][tid], lds_col[1][tid]);
  }

  // Final row-max reduce across the 16 column-lanes.
  #pragma unroll
  for (int mt = 0; mt < 4; ++mt)
    #pragma unroll
    for (int r = 0; r < 4; ++r) {
      float v = rmax[mt][r];
      #pragma unroll
      for (int off = 1; off < 16; off <<= 1)
        v = fmaxf(v, __shfl_xor(v, off, 64));
      if (fr == 0) lds_row[wn][wm * 64 + mt * 16 + hi * 4 + r] = v;
    }
  __syncthreads();
  if (tid < BM)
    row_part[(size_t)jg * B + ti * BM + tid] =
        fmaxf(lds_row[0][tid], lds_row[1][tid]);
}

// Kernel 3: reduce partial maxes -> M; threshold; per-row loss; one float
// atomicAdd of blocksum/B into d_out (zeroed by norm_kernel).
__global__ __launch_bounds__(256) void finalize_kernel(
    const float* __restrict__ row_part, const float* __restrict__ col_part,
    const float* __restrict__ diag, int B, int Trow, int Tcol,
    float* __restrict__ out) {
  const int v = blockIdx.x * 256 + threadIdx.x;
  const bool isrow = v < B;
  const int i = isrow ? v : v - B;
  const float* part = isrow ? row_part : col_part;
  const int T = isrow ? Trow : Tcol;
  float m = -1e9f;
  for (int t = 0; t < T; ++t) m = fmaxf(m, part[(size_t)t * B + i]);
  const float d = diag[i];
  float loss = 0.f;
  if ((d < 1.0f - 1e-5f) && (m + 0.2f > d)) {
    loss = fmaxf(0.2f * d * d - 0.7f * d + 0.5f, 0.f) +
           fmaxf(0.9f * m * m - 0.4f * m + 0.03f, 0.f);
  }
  for (int off = 1; off < 64; off <<= 1) loss += __shfl_xor(loss, off, 64);
  __shared__ float ssum[4];
  if ((threadIdx.x & 63) == 0) ssum[threadIdx.x >> 6] = loss;
  __syncthreads();
  if (threadIdx.x == 0)
    atomicAdd(out, (ssum[0] + ssum[1] + ssum[2] + ssum[3]) / (float)B);
}

extern "C" void kernel_launch(void* const* d_in, const int* in_sizes, int n_in,
                              void* d_out, int out_size, void* d_ws, size_t ws_size,
                              hipStream_t stream) {
  const float* a      = (const float*)d_in[0];
  const float* b      = (const float*)d_in[1];
  const int*   labels = (const int*)d_in[2];
  const int B = in_sizes[2];
  const int D = in_sizes[0] / B;       // expected 256 (== KD)
  const int ngroups = (B / BN) / NTJ;  // 8
  const int Tcol = B / BM;             // 64

  char* ws = (char*)d_ws;
  unsigned short* an = (unsigned short*)ws;                         // B*D*2
  unsigned short* bn = (unsigned short*)(ws + (size_t)B * D * 2);   // B*D*2
  float* diag     = (float*)(ws + (size_t)B * D * 4);               // B*4
  float* row_part = diag + B;                                       // ngroups*B*4
  float* col_part = row_part + (size_t)ngroups * B;                 // Tcol*B*4

  norm_kernel<<<B / 4, 256, 0, stream>>>(a, b, an, bn, diag, (float*)d_out, D);

  const int nblocks = (B / BM) * ngroups;   // 512
  gemm_max_kernel<<<nblocks, 256, 0, stream>>>(an, bn, labels,
                                               row_part, col_part, B, ngroups);

  finalize_kernel<<<(2 * B) / 256, 256, 0, stream>>>(
      row_part, col_part, diag, B, ngroups, Tcol, (float*)d_out);
}

// Round 4
// 137.741 us; speedup vs baseline: 1.3745x; 1.3745x over previous
//
#include <hip/hip_runtime.h>
#include <stdint.h>

#define BM 128
#define BN 128
#define KD 256     // K dimension; kernel assumes 256

typedef __attribute__((ext_vector_type(4))) float f32x4;
typedef __attribute__((ext_vector_type(4))) int   i32x4;
typedef __attribute__((ext_vector_type(8))) int   i32x8;

// Kernel 1: per-row normalize, convert to fp8 e4m3 (OCP, HW cvt); fp32 diag.
// Lane l handles elements [4l, 4l+4) of its wave's row. Also zeroes d_out.
__global__ __launch_bounds__(256) void norm_kernel(
    const float* __restrict__ a, const float* __restrict__ b,
    unsigned int* __restrict__ an, unsigned int* __restrict__ bn,
    float* __restrict__ diag, float* __restrict__ out, int D) {
  if (blockIdx.x == 0 && threadIdx.x == 0) out[0] = 0.f;
  const int row = blockIdx.x * 4 + (threadIdx.x >> 6);
  const int l = threadIdx.x & 63;
  const float4 av = ((const float4*)(a + (size_t)row * D))[l];
  const float4 bv = ((const float4*)(b + (size_t)row * D))[l];
  float ssa = av.x*av.x + av.y*av.y + av.z*av.z + av.w*av.w;
  float ssb = bv.x*bv.x + bv.y*bv.y + bv.z*bv.z + bv.w*bv.w;
  float dot = av.x*bv.x + av.y*bv.y + av.z*bv.z + av.w*bv.w;
  for (int off = 1; off < 64; off <<= 1) {
    ssa += __shfl_xor(ssa, off, 64);
    ssb += __shfl_xor(ssb, off, 64);
    dot += __shfl_xor(dot, off, 64);
  }
  const float inva = 1.0f / sqrtf(ssa);
  const float invb = 1.0f / sqrtf(ssb);
  if (l == 0) diag[row] = dot * inva * invb;
  int pa = 0, pb = 0;
  pa = __builtin_amdgcn_cvt_pk_fp8_f32(av.x * inva, av.y * inva, pa, 0);
  pa = __builtin_amdgcn_cvt_pk_fp8_f32(av.z * inva, av.w * inva, pa, 1);
  pb = __builtin_amdgcn_cvt_pk_fp8_f32(bv.x * invb, bv.y * invb, pb, 0);
  pb = __builtin_amdgcn_cvt_pk_fp8_f32(bv.z * invb, bv.w * invb, pb, 1);
  an[(size_t)row * (D / 4) + l] = (unsigned int)pa;
  bn[(size_t)row * (D / 4) + l] = (unsigned int)pb;
}

// Kernel 2: 128x128 fp8 tile via mfma_scale_f32_16x16x128_f8f6f4 (scale=1.0).
// Both K=128 halves staged upfront into a double buffer -> ONE barrier before
// compute. LDS XOR-swizzled at 16B-chunk granularity (chunk g of row r stored
// at g ^ (r&7); applied on the global source side since global_load_lds's LDS
// destination must stay lane-contiguous). Row stride 128B -> bank group is
// determined by chunk position alone, and positions c^(fr&7) over the 16
// fragment rows cover all 8 groups twice -> 2-way (free).
// Epilogue: label-masked row/col max partials (threshold lives in finalize).
__global__ __launch_bounds__(256, 2) void gemm_max_kernel(
    const unsigned char* __restrict__ an, const unsigned char* __restrict__ bn,
    const int* __restrict__ labels,
    float* __restrict__ row_part, float* __restrict__ col_part, int B) {
  __shared__ __align__(16) unsigned char sA[2][BM * 128];   // 2 x 16 KB
  __shared__ __align__(16) unsigned char sB[2][BN * 128];   // 2 x 16 KB
  __shared__ float lds_row[2][BM];
  __shared__ float lds_col[2][BN];

  const int tid  = threadIdx.x;
  const int lane = tid & 63;
  const int w    = tid >> 6;
  const int wm   = w >> 1, wn = w & 1;
  const int tj   = blockIdx.x & 63;        // fast-varying: per-XCD B-tile reuse
  const int ti   = blockIdx.x >> 6;

  // Stage all of K=256 (both halves) before the single barrier.
  const int sr  = lane >> 3;     // row within 8-row chunk
  const int sc8 = lane & 7;      // 16B-chunk position in the 128B row
  const int ssw = (sc8 ^ sr) * 16;   // swizzled source byte offset ((row&7)==sr)
  #pragma unroll
  for (int it = 0; it < 2; ++it) {
    #pragma unroll
    for (int c = 0; c < 4; ++c) {
      const int r0 = w * 32 + c * 8;
      const unsigned char* ga = an + (size_t)(ti * BM + r0 + sr) * KD + it * 128 + ssw;
      const unsigned char* gb = bn + (size_t)(tj * BN + r0 + sr) * KD + it * 128 + ssw;
      __builtin_amdgcn_global_load_lds(
          (const __attribute__((address_space(1))) void*)ga,
          (__attribute__((address_space(3))) void*)(&sA[it][r0 * 128] + lane * 16), 16, 0, 0);
      __builtin_amdgcn_global_load_lds(
          (const __attribute__((address_space(1))) void*)gb,
          (__attribute__((address_space(3))) void*)(&sB[it][r0 * 128] + lane * 16), 16, 0, 0);
    }
  }

  const int fr = lane & 15;      // fragment m/n index
  const int hi = lane >> 4;      // k-block quad: lane holds k = hi*32 .. +31
  const int p0 = ((2 * hi)     ^ (fr & 7)) * 16;   // deswizzled chunk offsets
  const int p1 = ((2 * hi + 1) ^ (fr & 7)) * 16;

  // Labels while DMA is in flight.
  int li[4][4], labc[4];
  #pragma unroll
  for (int mt = 0; mt < 4; ++mt)
    #pragma unroll
    for (int r = 0; r < 4; ++r)
      li[mt][r] = labels[ti * BM + wm * 64 + mt * 16 + hi * 4 + r];
  #pragma unroll
  for (int nt = 0; nt < 4; ++nt)
    labc[nt] = labels[tj * BN + wn * 64 + nt * 16 + fr];

  f32x4 acc[4][4];
  #pragma unroll
  for (int mt = 0; mt < 4; ++mt)
    #pragma unroll
    for (int nt = 0; nt < 4; ++nt)
      acc[mt][nt] = (f32x4){0.f, 0.f, 0.f, 0.f};

  __syncthreads();   // the one staging barrier

  const int SC = 0x7F7F7F7F;     // E8M0 scales = 1.0 for all four byte slots
  #pragma unroll
  for (int it = 0; it < 2; ++it) {
    i32x8 af[4], bf[4];
    #pragma unroll
    for (int t = 0; t < 4; ++t) {
      const unsigned char* ra = &sA[it][(wm * 64 + t * 16 + fr) * 128];
      const unsigned char* rb = &sB[it][(wn * 64 + t * 16 + fr) * 128];
      i32x4 alo = *(const i32x4*)(ra + p0), ahi = *(const i32x4*)(ra + p1);
      i32x4 blo = *(const i32x4*)(rb + p0), bhi = *(const i32x4*)(rb + p1);
      af[t] = __builtin_shufflevector(alo, ahi, 0, 1, 2, 3, 4, 5, 6, 7);
      bf[t] = __builtin_shufflevector(blo, bhi, 0, 1, 2, 3, 4, 5, 6, 7);
    }
    #pragma unroll
    for (int mt = 0; mt < 4; ++mt)
      #pragma unroll
      for (int nt = 0; nt < 4; ++nt)
        acc[mt][nt] = __builtin_amdgcn_mfma_scale_f32_16x16x128_f8f6f4(
            af[mt], bf[nt], acc[mt][nt], 0, 0, 0, SC, 0, SC);
  }

  // Epilogue: label-masked max. C/D: col = lane&15, row = hi*4 + reg.
  float cmax[4] = {-1e9f, -1e9f, -1e9f, -1e9f};
  #pragma unroll
  for (int mt = 0; mt < 4; ++mt)
    #pragma unroll
    for (int r = 0; r < 4; ++r) {
      const int l0 = li[mt][r];
      float rmax = -1e9f;
      #pragma unroll
      for (int nt = 0; nt < 4; ++nt) {
        const float vm = (l0 != labc[nt]) ? acc[mt][nt][r] : -1e9f;
        rmax = fmaxf(rmax, vm);
        cmax[nt] = fmaxf(cmax[nt], vm);
      }
      #pragma unroll
      for (int off = 1; off < 16; off <<= 1)
        rmax = fmaxf(rmax, __shfl_xor(rmax, off, 64));
      if (fr == 0) lds_row[wn][wm * 64 + mt * 16 + hi * 4 + r] = rmax;
    }
  #pragma unroll
  for (int nt = 0; nt < 4; ++nt) {
    float c = cmax[nt];
    c = fmaxf(c, __shfl_xor(c, 16, 64));
    c = fmaxf(c, __shfl_xor(c, 32, 64));
    if (hi == 0) lds_col[wm][wn * 64 + nt * 16 + fr] = c;
  }
  __syncthreads();
  if (tid < BM)
    row_part[(size_t)tj * B + ti * BM + tid] =
        fmaxf(lds_row[0][tid], lds_row[1][tid]);
  else if (tid < BM + BN) {
    const int t2 = tid - BM;
    col_part[(size_t)ti * B + tj * BN + t2] =
        fmaxf(lds_col[0][t2], lds_col[1][t2]);
  }
}

// Kernel 3: reduce per-tile maxes -> M; hard-negative threshold + pos_valid;
// per-row loss; one float atomicAdd of blocksum/B into d_out (zeroed by norm).
__global__ __launch_bounds__(256) void finalize_kernel(
    const float* __restrict__ row_part, const float* __restrict__ col_part,
    const float* __restrict__ diag, int B, int T, float* __restrict__ out) {
  const int v = blockIdx.x * 256 + threadIdx.x;
  const bool isrow = v < B;
  const int i = isrow ? v : v - B;
  const float* part = isrow ? row_part : col_part;
  float m = -1e9f;
  for (int t = 0; t < T; ++t) m = fmaxf(m, part[(size_t)t * B + i]);
  const float d = diag[i];
  float loss = 0.f;
  if ((d < 1.0f - 1e-5f) && (m + 0.2f > d)) {
    loss = fmaxf(0.2f * d * d - 0.7f * d + 0.5f, 0.f) +
           fmaxf(0.9f * m * m - 0.4f * m + 0.03f, 0.f);
  }
  for (int off = 1; off < 64; off <<= 1) loss += __shfl_xor(loss, off, 64);
  __shared__ float ssum[4];
  if ((threadIdx.x & 63) == 0) ssum[threadIdx.x >> 6] = loss;
  __syncthreads();
  if (threadIdx.x == 0)
    atomicAdd(out, (ssum[0] + ssum[1] + ssum[2] + ssum[3]) / (float)B);
}

extern "C" void kernel_launch(void* const* d_in, const int* in_sizes, int n_in,
                              void* d_out, int out_size, void* d_ws, size_t ws_size,
                              hipStream_t stream) {
  const float* a      = (const float*)d_in[0];
  const float* b      = (const float*)d_in[1];
  const int*   labels = (const int*)d_in[2];
  const int B = in_sizes[2];
  const int D = in_sizes[0] / B;       // 256
  const int T = B / BM;                // 64 partial slots per direction

  char* ws = (char*)d_ws;
  unsigned char* an = (unsigned char*)ws;                    // B*D fp8
  unsigned char* bn = (unsigned char*)(ws + (size_t)B * D);  // B*D fp8
  float* diag     = (float*)(ws + (size_t)2 * B * D);        // B*4
  float* row_part = diag + B;                                // T*B*4
  float* col_part = row_part + (size_t)T * B;                // T*B*4

  norm_kernel<<<B / 4, 256, 0, stream>>>(a, b, (unsigned int*)an,
                                         (unsigned int*)bn, diag,
                                         (float*)d_out, D);

  gemm_max_kernel<<<(B / BM) * (B / BN), 256, 0, stream>>>(
      an, bn, labels, row_part, col_part, B);

  finalize_kernel<<<(2 * B) / 256, 256, 0, stream>>>(
      row_part, col_part, diag, B, T, (float*)d_out);
}

// Round 5
// 121.131 us; speedup vs baseline: 1.5630x; 1.1371x over previous
//
#include <hip/hip_runtime.h>
#include <stdint.h>

#define BM 128
#define BN 128
#define KD 256     // K dimension; kernel assumes 256

typedef __attribute__((ext_vector_type(4))) float f32x4;
typedef __attribute__((ext_vector_type(4))) int   i32x4;
typedef __attribute__((ext_vector_type(8))) int   i32x8;

__device__ __forceinline__ float fmax4(f32x4 v) {
  return fmaxf(fmaxf(v[0], v[1]), fmaxf(v[2], v[3]));
}

// Kernel 1: per-row normalize, convert to fp8 e4m3 (OCP HW cvt); fp32 diag.
// Lane l handles elements [4l, 4l+4). Also zeroes d_out.
__global__ __launch_bounds__(256) void norm_kernel(
    const float* __restrict__ a, const float* __restrict__ b,
    unsigned int* __restrict__ an, unsigned int* __restrict__ bn,
    float* __restrict__ diag, float* __restrict__ out, int D) {
  if (blockIdx.x == 0 && threadIdx.x == 0) out[0] = 0.f;
  const int row = blockIdx.x * 4 + (threadIdx.x >> 6);
  const int l = threadIdx.x & 63;
  const float4 av = ((const float4*)(a + (size_t)row * D))[l];
  const float4 bv = ((const float4*)(b + (size_t)row * D))[l];
  float ssa = av.x*av.x + av.y*av.y + av.z*av.z + av.w*av.w;
  float ssb = bv.x*bv.x + bv.y*bv.y + bv.z*bv.z + bv.w*bv.w;
  float dot = av.x*bv.x + av.y*bv.y + av.z*bv.z + av.w*bv.w;
  for (int off = 1; off < 64; off <<= 1) {
    ssa += __shfl_xor(ssa, off, 64);
    ssb += __shfl_xor(ssb, off, 64);
    dot += __shfl_xor(dot, off, 64);
  }
  const float inva = 1.0f / sqrtf(ssa);
  const float invb = 1.0f / sqrtf(ssb);
  if (l == 0) diag[row] = dot * inva * invb;
  int pa = 0, pb = 0;
  pa = __builtin_amdgcn_cvt_pk_fp8_f32(av.x * inva, av.y * inva, pa, 0);
  pa = __builtin_amdgcn_cvt_pk_fp8_f32(av.z * inva, av.w * inva, pa, 1);
  pb = __builtin_amdgcn_cvt_pk_fp8_f32(bv.x * invb, bv.y * invb, pb, 0);
  pb = __builtin_amdgcn_cvt_pk_fp8_f32(bv.z * invb, bv.w * invb, pb, 1);
  an[(size_t)row * (D / 4) + l] = (unsigned int)pa;
  bn[(size_t)row * (D / 4) + l] = (unsigned int)pb;
}

// Kernel 2: 128x128 fp8 tile, mfma_scale_f32_16x16x128_f8f6f4, scale=1.0.
// BK=128, TWO K-iterations through a single 32 KB LDS buffer -> 33 KB/block
// -> 4 blocks/CU (16 waves) for latency hiding. XOR swizzle at 16B-chunk
// granularity: chunk g of row r stored at g^(r&7), applied on the GLOBAL
// source side (global_load_lds LDS dest must be lane-contiguous).
// Epilogue: nt folded in-register; per-lane row partials go through an
// XOR-swizzled red[128][32] overlay on dead sA (write 2-way=free, read b128
// uniform) instead of 64 shuffles/wave; col partials via 2 shuffles each.
__global__ __launch_bounds__(256, 4) void gemm_max_kernel(
    const unsigned char* __restrict__ an, const unsigned char* __restrict__ bn,
    const int* __restrict__ labels,
    float* __restrict__ row_part, float* __restrict__ col_part, int B) {
  __shared__ __align__(16) unsigned char sA[BM * 128];   // 16 KB (red overlay later)
  __shared__ __align__(16) unsigned char sB[BN * 128];   // 16 KB
  __shared__ float lds_col[2][BN];                       // 1 KB

  const int tid  = threadIdx.x;
  const int lane = tid & 63;
  const int w    = tid >> 6;
  const int wm   = w >> 1, wn = w & 1;
  const int tj   = blockIdx.x & 63;     // fast-varying: B-tile L2 reuse
  const int ti   = blockIdx.x >> 6;

  // staging decomposition
  const int sr  = lane >> 3;            // row within 8-row chunk
  const int sc8 = lane & 7;             // dst 16B-chunk position
  const int ssw = (sc8 ^ sr) * 16;      // swizzled source byte offset

  // fragment decomposition
  const int fr = lane & 15;             // m/n index
  const int hi = lane >> 4;             // k-quad: lane holds k = hi*32..+31
  const int p0 = ((2 * hi)     ^ (fr & 7)) * 16;
  const int p1 = ((2 * hi + 1) ^ (fr & 7)) * 16;

  f32x4 acc[4][4];
  #pragma unroll
  for (int mt = 0; mt < 4; ++mt)
    #pragma unroll
    for (int nt = 0; nt < 4; ++nt)
      acc[mt][nt] = (f32x4){0.f, 0.f, 0.f, 0.f};

  const int SC = 0x7F7F7F7F;            // E8M0 = 1.0 in all byte slots

  #pragma unroll
  for (int it = 0; it < 2; ++it) {
    #pragma unroll
    for (int c = 0; c < 4; ++c) {
      const int r0 = w * 32 + c * 8;
      const unsigned char* ga = an + (size_t)(ti * BM + r0 + sr) * KD + it * 128 + ssw;
      const unsigned char* gb = bn + (size_t)(tj * BN + r0 + sr) * KD + it * 128 + ssw;
      __builtin_amdgcn_global_load_lds(
          (const __attribute__((address_space(1))) void*)ga,
          (__attribute__((address_space(3))) void*)(sA + r0 * 128 + lane * 16), 16, 0, 0);
      __builtin_amdgcn_global_load_lds(
          (const __attribute__((address_space(1))) void*)gb,
          (__attribute__((address_space(3))) void*)(sB + r0 * 128 + lane * 16), 16, 0, 0);
    }
    __syncthreads();

    i32x8 bf[4];
    #pragma unroll
    for (int nt = 0; nt < 4; ++nt) {
      const unsigned char* rb = sB + (wn * 64 + nt * 16 + fr) * 128;
      i32x4 blo = *(const i32x4*)(rb + p0), bhi = *(const i32x4*)(rb + p1);
      bf[nt] = __builtin_shufflevector(blo, bhi, 0, 1, 2, 3, 4, 5, 6, 7);
    }
    #pragma unroll
    for (int mt = 0; mt < 4; ++mt) {
      const unsigned char* ra = sA + (wm * 64 + mt * 16 + fr) * 128;
      i32x4 alo = *(const i32x4*)(ra + p0), ahi = *(const i32x4*)(ra + p1);
      i32x8 af = __builtin_shufflevector(alo, ahi, 0, 1, 2, 3, 4, 5, 6, 7);
      #pragma unroll
      for (int nt = 0; nt < 4; ++nt)
        acc[mt][nt] = __builtin_amdgcn_mfma_scale_f32_16x16x128_f8f6f4(
            af, bf[nt], acc[mt][nt], 0, 0, 0, SC, 0, SC);
    }
    __syncthreads();   // it=0: sA/sB free for restage; it=1: free for red overlay
  }

  // ---- Epilogue ----
  // Labels loaded only now (keeps compute-phase VGPR <= 128).
  int li[4][4], labc[4];
  #pragma unroll
  for (int mt = 0; mt < 4; ++mt)
    #pragma unroll
    for (int r = 0; r < 4; ++r)
      li[mt][r] = labels[ti * BM + wm * 64 + mt * 16 + hi * 4 + r];
  #pragma unroll
  for (int nt = 0; nt < 4; ++nt)
    labc[nt] = labels[tj * BN + wn * 64 + nt * 16 + fr];

  // Per-lane masked partials; nt folded in-register.
  float rp[4][4];
  float cp[4] = {-1e9f, -1e9f, -1e9f, -1e9f};
  #pragma unroll
  for (int mt = 0; mt < 4; ++mt)
    #pragma unroll
    for (int r = 0; r < 4; ++r) {
      const int l0 = li[mt][r];
      float rm = -1e9f;
      #pragma unroll
      for (int nt = 0; nt < 4; ++nt) {
        const float vm = (l0 != labc[nt]) ? acc[mt][nt][r] : -1e9f;
        rm = fmaxf(rm, vm);
        cp[nt] = fmaxf(cp[nt], vm);
      }
      rp[mt][r] = rm;
    }

  // Row partials -> red[128][32] overlay on sA, XOR-swizzled at 16B chunks:
  // slot s (=wn*16+fr) of row i stored at chunk (s>>2)^(i&7), word s&3.
  float* red = (float*)sA;
  const int s = wn * 16 + fr;
  #pragma unroll
  for (int mt = 0; mt < 4; ++mt)
    #pragma unroll
    for (int r = 0; r < 4; ++r) {
      const int i = wm * 64 + mt * 16 + hi * 4 + r;
      red[i * 32 + (((s >> 2) ^ (i & 7)) << 2) + (s & 3)] = rp[mt][r];
    }

  // Col partials: reduce over the 4 hi lanes sharing a column (2 shuffles).
  #pragma unroll
  for (int nt = 0; nt < 4; ++nt) {
    float c = cp[nt];
    c = fmaxf(c, __shfl_xor(c, 16, 64));
    c = fmaxf(c, __shfl_xor(c, 32, 64));
    if (hi == 0) lds_col[wm][wn * 64 + nt * 16 + fr] = c;
  }
  __syncthreads();

  if (tid < BM) {
    const int key = tid & 7;
    const f32x4* rr = (const f32x4*)(red + tid * 32);
    f32x4 m4 = rr[0 ^ key];
    #pragma unroll
    for (int k = 1; k < 8; ++k) {
      f32x4 v = rr[k ^ key];
      m4[0] = fmaxf(m4[0], v[0]); m4[1] = fmaxf(m4[1], v[1]);
      m4[2] = fmaxf(m4[2], v[2]); m4[3] = fmaxf(m4[3], v[3]);
    }
    row_part[(size_t)tj * B + ti * BM + tid] = fmax4(m4);
  } else if (tid < BM + BN) {
    const int t2 = tid - BM;
    col_part[(size_t)ti * B + tj * BN + t2] =
        fmaxf(lds_col[0][t2], lds_col[1][t2]);
  }
}

// Kernel 3: reduce per-tile maxes -> M; hard-negative threshold + pos_valid;
// per-row loss; one float atomicAdd of blocksum/B into d_out (zeroed by norm).
__global__ __launch_bounds__(256) void finalize_kernel(
    const float* __restrict__ row_part, const float* __restrict__ col_part,
    const float* __restrict__ diag, int B, int T, float* __restrict__ out) {
  const int v = blockIdx.x * 256 + threadIdx.x;
  const bool isrow = v < B;
  const int i = isrow ? v : v - B;
  const float* part = isrow ? row_part : col_part;
  float m = -1e9f;
  for (int t = 0; t < T; ++t) m = fmaxf(m, part[(size_t)t * B + i]);
  const float d = diag[i];
  float loss = 0.f;
  if ((d < 1.0f - 1e-5f) && (m + 0.2f > d)) {
    loss = fmaxf(0.2f * d * d - 0.7f * d + 0.5f, 0.f) +
           fmaxf(0.9f * m * m - 0.4f * m + 0.03f, 0.f);
  }
  for (int off = 1; off < 64; off <<= 1) loss += __shfl_xor(loss, off, 64);
  __shared__ float ssum[4];
  if ((threadIdx.x & 63) == 0) ssum[threadIdx.x >> 6] = loss;
  __syncthreads();
  if (threadIdx.x == 0)
    atomicAdd(out, (ssum[0] + ssum[1] + ssum[2] + ssum[3]) / (float)B);
}

extern "C" void kernel_launch(void* const* d_in, const int* in_sizes, int n_in,
                              void* d_out, int out_size, void* d_ws, size_t ws_size,
                              hipStream_t stream) {
  const float* a      = (const float*)d_in[0];
  const float* b      = (const float*)d_in[1];
  const int*   labels = (const int*)d_in[2];
  const int B = in_sizes[2];
  const int D = in_sizes[0] / B;       // 256
  const int T = B / BM;                // 64 partial slots per direction

  char* ws = (char*)d_ws;
  unsigned char* an = (unsigned char*)ws;                    // B*D fp8
  unsigned char* bn = (unsigned char*)(ws + (size_t)B * D);  // B*D fp8
  float* diag     = (float*)(ws + (size_t)2 * B * D);        // B*4
  float* row_part = diag + B;                                // T*B*4
  float* col_part = row_part + (size_t)T * B;                // T*B*4

  norm_kernel<<<B / 4, 256, 0, stream>>>(a, b, (unsigned int*)an,
                                         (unsigned int*)bn, diag,
                                         (float*)d_out, D);

  gemm_max_kernel<<<(B / BM) * (B / BN), 256, 0, stream>>>(
      an, bn, labels, row_part, col_part, B);

  finalize_kernel<<<(2 * B) / 256, 256, 0, stream>>>(
      row_part, col_part, diag, B, T, (float*)d_out);
}